// Round 1
// baseline (750.526 us; speedup 1.0000x reference)
//
#include <hip/hip_runtime.h>
#include <cstdint>
#include <cstddef>

typedef __bf16 bf16x8 __attribute__((ext_vector_type(8)));
typedef float  f32x4  __attribute__((ext_vector_type(4)));

#define S_TXT 256
#define S_IMG 2048
#define S_TOT 2304
#define NHEAD 24
#define HDIM  128
#define DMODEL 3072

static constexpr size_t SZ_QKV  = (size_t)NHEAD * S_TOT * HDIM;   // 7,077,888
static constexpr size_t SZ_AO   = (size_t)S_TOT * DMODEL;         // 7,077,888
static constexpr size_t SZ_XIMG = (size_t)S_IMG * DMODEL;         // 6,291,456
static constexpr size_t SZ_XTXT = (size_t)S_TXT * DMODEL;         //   786,432
static constexpr size_t SZ_W    = (size_t)DMODEL * DMODEL;        // 9,437,184

__device__ __forceinline__ f32x4 mfma16(bf16x8 a, bf16x8 b, f32x4 c) {
  return __builtin_amdgcn_mfma_f32_16x16x32_bf16(a, b, c, 0, 0, 0);
}

// ---------------- fp32 -> bf16 convert (RNE) ----------------
__global__ __launch_bounds__(256) void cvt_f32_bf16(const float* __restrict__ in,
                                                    __bf16* __restrict__ out, int n) {
  int i = (blockIdx.x * 256 + threadIdx.x) * 8;
  if (i + 8 > n) return;
  f32x4 a = *(const f32x4*)(in + i);
  f32x4 b = *(const f32x4*)(in + i + 4);
  bf16x8 r;
  r[0]=(__bf16)a[0]; r[1]=(__bf16)a[1]; r[2]=(__bf16)a[2]; r[3]=(__bf16)a[3];
  r[4]=(__bf16)b[0]; r[5]=(__bf16)b[1]; r[6]=(__bf16)b[2]; r[7]=(__bf16)b[3];
  *(bf16x8*)(out + i) = r;
}

// ---------------- RoPE in-place on [24][2304][128] bf16 ----------------
__global__ __launch_bounds__(256) void rope_kernel(__bf16* __restrict__ Qb, __bf16* __restrict__ Kb,
    const float* __restrict__ icos, const float* __restrict__ isin,
    const float* __restrict__ tcos, const float* __restrict__ tsin) {
  size_t idx = ((size_t)blockIdx.x * 256 + threadIdx.x) * 8;
  __bf16* X = blockIdx.y ? Kb : Qb;
  int d = (int)(idx & 127);
  int s = (int)((idx >> 7) % S_TOT);
  const float *cp, *sp; int ss;
  if (s < S_TXT) { cp = tcos; sp = tsin; ss = s; }
  else           { cp = icos; sp = isin; ss = s - S_TXT; }
  const float* cb = cp + (size_t)ss * HDIM + d;
  const float* sb = sp + (size_t)ss * HDIM + d;
  f32x4 c0 = *(const f32x4*)(cb);
  f32x4 c1 = *(const f32x4*)(cb + 4);
  f32x4 s0 = *(const f32x4*)(sb);
  f32x4 s1 = *(const f32x4*)(sb + 4);
  bf16x8 x = *(const bf16x8*)(X + idx);
  float xf[8];
  #pragma unroll
  for (int j = 0; j < 8; ++j) xf[j] = (float)x[j];
  bf16x8 o;
  o[0] = (__bf16)(xf[0]*c0[0] - xf[1]*s0[0]);
  o[1] = (__bf16)(xf[1]*c0[1] + xf[0]*s0[1]);
  o[2] = (__bf16)(xf[2]*c0[2] - xf[3]*s0[2]);
  o[3] = (__bf16)(xf[3]*c0[3] + xf[2]*s0[3]);
  o[4] = (__bf16)(xf[4]*c1[0] - xf[5]*s1[0]);
  o[5] = (__bf16)(xf[5]*c1[1] + xf[4]*s1[1]);
  o[6] = (__bf16)(xf[6]*c1[2] - xf[7]*s1[2]);
  o[7] = (__bf16)(xf[7]*c1[3] + xf[6]*s1[3]);
  *(bf16x8*)(X + idx) = o;
}

// ---------------- V [h][s][d] -> Vt [h][d][s] ----------------
__global__ __launch_bounds__(128) void transpose_v(const __bf16* __restrict__ V,
                                                   __bf16* __restrict__ Vt) {
  int h = blockIdx.y, s0 = blockIdx.x * 64, d = threadIdx.x;   // 128 threads
  const __bf16* src = V + ((size_t)h * S_TOT + s0) * HDIM + d;
  __bf16 tmp[64];
  #pragma unroll
  for (int k = 0; k < 64; ++k) tmp[k] = src[(size_t)k * HDIM];
  __bf16* dst = Vt + ((size_t)h * HDIM + d) * S_TOT + s0;
  #pragma unroll
  for (int k = 0; k < 8; ++k) {
    bf16x8 v;
    #pragma unroll
    for (int j = 0; j < 8; ++j) v[j] = tmp[k*8 + j];
    *(bf16x8*)(dst + k*8) = v;
  }
}

// ---------------- GEMM: C[M,N=3072] = A[M,K] * B[N,K]^T + bias ----------------
// MODE 0: bf16 out scattered to [head][s_off+m][hd]; MODE 1: fp32 row-major out.
template<int MODE>
__global__ __launch_bounds__(256, 2) void gemm_bt(
    const __bf16* __restrict__ A, const __bf16* __restrict__ B,
    const float* __restrict__ bias, void* __restrict__ Cout,
    int M, int K, int s_off)
{
  const int tid = threadIdx.x;
  const int lane = tid & 63, wave = tid >> 6;
  const int wr = wave >> 1, wc = wave & 1;
  const int g = lane >> 4, lr = lane & 15;
  const int m0 = blockIdx.x * 128, n0 = blockIdx.y * 128;

  // +8 elem (16B) row pad: frag ds_read_b128 and staging ds_write_b128 ~2-way max
  __shared__ __align__(16) __bf16 As[128 * 40];
  __shared__ __align__(16) __bf16 Bs[128 * 40];

  const int arow = tid >> 2;   // 0..63
  const int ac   = tid & 3;    // 16B chunk within BK=32 row
  const __bf16* Ap = A + (size_t)(m0 + arow) * K + ac * 8;
  const __bf16* Bp = B + (size_t)(n0 + arow) * K + ac * 8;

  f32x4 acc[4][4];
  #pragma unroll
  for (int i = 0; i < 4; ++i)
    #pragma unroll
    for (int j = 0; j < 4; ++j) acc[i][j] = (f32x4){0.f,0.f,0.f,0.f};

  bf16x8 ar0 = *(const bf16x8*)(Ap);
  bf16x8 ar1 = *(const bf16x8*)(Ap + (size_t)64 * K);
  bf16x8 br0 = *(const bf16x8*)(Bp);
  bf16x8 br1 = *(const bf16x8*)(Bp + (size_t)64 * K);

  const int nk = K / 32;
  for (int kt = 0; kt < nk; ++kt) {
    asm volatile("" ::: "memory");
    __builtin_amdgcn_s_barrier();          // all waves done reading prev tile
    asm volatile("" ::: "memory");
    *(bf16x8*)(As + (arow     ) * 40 + ac * 8) = ar0;
    *(bf16x8*)(As + (arow + 64) * 40 + ac * 8) = ar1;
    *(bf16x8*)(Bs + (arow     ) * 40 + ac * 8) = br0;
    *(bf16x8*)(Bs + (arow + 64) * 40 + ac * 8) = br1;
    if (kt + 1 < nk) {                     // prefetch stays in flight across barrier
      const __bf16* Ap2 = Ap + (kt + 1) * 32;
      const __bf16* Bp2 = Bp + (kt + 1) * 32;
      ar0 = *(const bf16x8*)(Ap2);
      ar1 = *(const bf16x8*)(Ap2 + (size_t)64 * K);
      br0 = *(const bf16x8*)(Bp2);
      br1 = *(const bf16x8*)(Bp2 + (size_t)64 * K);
    }
    asm volatile("s_waitcnt lgkmcnt(0)" ::: "memory");  // LDS writes visible; no vmcnt drain
    __builtin_amdgcn_s_barrier();
    asm volatile("" ::: "memory");

    bf16x8 af[4], bfr[4];
    #pragma unroll
    for (int i = 0; i < 4; ++i) {
      af[i]  = *(const bf16x8*)(As + (wr*64 + i*16 + lr) * 40 + g * 8);
      bfr[i] = *(const bf16x8*)(Bs + (wc*64 + i*16 + lr) * 40 + g * 8);
    }
    #pragma unroll
    for (int i = 0; i < 4; ++i)
      #pragma unroll
      for (int j = 0; j < 4; ++j)
        acc[i][j] = mfma16(af[i], bfr[j], acc[i][j]);
  }

  float bv[4];
  #pragma unroll
  for (int j = 0; j < 4; ++j) bv[j] = bias[n0 + wc*64 + j*16 + lr];

  if (MODE == 0) {
    __bf16* Qp = (__bf16*)Cout;
    const int head = n0 >> 7;                      // N-tile==128 -> exactly one head
    #pragma unroll
    for (int i = 0; i < 4; ++i)
      #pragma unroll
      for (int j = 0; j < 4; ++j)
        #pragma unroll
        for (int r = 0; r < 4; ++r) {
          int s  = s_off + m0 + wr*64 + i*16 + g*4 + r;
          int hd = wc*64 + j*16 + lr;
          Qp[((size_t)head * S_TOT + s) * HDIM + hd] = (__bf16)(acc[i][j][r] + bv[j]);
        }
  } else {
    float* Cf = (float*)Cout;
    #pragma unroll
    for (int i = 0; i < 4; ++i)
      #pragma unroll
      for (int j = 0; j < 4; ++j)
        #pragma unroll
        for (int r = 0; r < 4; ++r) {
          int m = m0 + wr*64 + i*16 + g*4 + r;
          int n = n0 + wc*64 + j*16 + lr;
          Cf[(size_t)m * DMODEL + n] = acc[i][j][r] + bv[j];
        }
  }
}

// ---------------- flash attention ----------------
// grid (36 qtiles, 24 heads), 256 thr = 4 waves x 16 q-rows, KV tile 64.
__global__ __launch_bounds__(256, 2) void flash_attn(
    const __bf16* __restrict__ Qg, const __bf16* __restrict__ Kg,
    const __bf16* __restrict__ Vt, __bf16* __restrict__ Og)
{
  const float scale = 0.08838834764831845f;  // 1/sqrt(128)
  const int h = blockIdx.y;
  const int q0 = blockIdx.x * 64;
  const int tid = threadIdx.x;
  const int lane = tid & 63, wave = tid >> 6;
  const int g = lane >> 4, lr = lane & 15;

  __shared__ __align__(16) __bf16 Kl[64 * 136];     // [kv][128 +8 pad]
  __shared__ __align__(16) __bf16 Vl[128 * 72];     // [d][64 +8 pad]
  __shared__ __align__(16) __bf16 Pl[4][16 * 72];   // per-wave [q][64 +8 pad]

  bf16x8 qf[4];
  {
    const __bf16* qp = Qg + ((size_t)h * S_TOT + q0 + wave*16 + lr) * HDIM + g * 8;
    #pragma unroll
    for (int kb = 0; kb < 4; ++kb) qf[kb] = *(const bf16x8*)(qp + kb * 32);
  }

  f32x4 acc[8];
  #pragma unroll
  for (int i = 0; i < 8; ++i) acc[i] = (f32x4){0.f,0.f,0.f,0.f};
  float mrow[4] = {-__builtin_inff(), -__builtin_inff(), -__builtin_inff(), -__builtin_inff()};
  float lrow[4] = {0.f, 0.f, 0.f, 0.f};

  const int krow = tid >> 4, kc = tid & 15;   // K stage: 16 rows x 16 chunks per iter
  const int vrow = tid >> 3, vc = tid & 7;    // V stage: 32 rows x 8 chunks per iter
  const __bf16* Kbase = Kg + (size_t)h * S_TOT * HDIM;
  const __bf16* Vbase = Vt + (size_t)h * HDIM * S_TOT;

  bf16x8 kreg[4], vreg[4];
  #pragma unroll
  for (int i = 0; i < 4; ++i) {
    kreg[i] = *(const bf16x8*)(Kbase + (size_t)(i*16 + krow) * HDIM + kc * 8);
    vreg[i] = *(const bf16x8*)(Vbase + (size_t)(i*32 + vrow) * S_TOT + vc * 8);
  }

  __bf16* Pw = &Pl[wave][0];

  for (int t = 0; t < S_TOT / 64; ++t) {
    asm volatile("" ::: "memory");
    __builtin_amdgcn_s_barrier();
    asm volatile("" ::: "memory");
    #pragma unroll
    for (int i = 0; i < 4; ++i) {
      *(bf16x8*)(Kl + (i*16 + krow) * 136 + kc * 8) = kreg[i];
      *(bf16x8*)(Vl + (i*32 + vrow) * 72  + vc * 8) = vreg[i];
    }
    if (t + 1 < S_TOT / 64) {
      int kv1 = (t + 1) * 64;
      #pragma unroll
      for (int i = 0; i < 4; ++i) {
        kreg[i] = *(const bf16x8*)(Kbase + (size_t)(kv1 + i*16 + krow) * HDIM + kc * 8);
        vreg[i] = *(const bf16x8*)(Vbase + (size_t)(i*32 + vrow) * S_TOT + kv1 + vc * 8);
      }
    }
    asm volatile("s_waitcnt lgkmcnt(0)" ::: "memory");
    __builtin_amdgcn_s_barrier();
    asm volatile("" ::: "memory");

    // QK^T : sc[kb] rows q=g*4+r, col kv=kb*16+lr
    f32x4 sc[4];
    #pragma unroll
    for (int kb = 0; kb < 4; ++kb) {
      f32x4 s4 = (f32x4){0.f,0.f,0.f,0.f};
      #pragma unroll
      for (int dk = 0; dk < 4; ++dk) {
        bf16x8 kf = *(const bf16x8*)(Kl + (kb*16 + lr) * 136 + (dk*4 + g) * 8);
        s4 = mfma16(qf[dk], kf, s4);
      }
      sc[kb] = s4;
    }

    // online softmax (fp32)
    float alpha[4];
    #pragma unroll
    for (int r = 0; r < 4; ++r) {
      float mx = fmaxf(fmaxf(sc[0][r], sc[1][r]), fmaxf(sc[2][r], sc[3][r])) * scale;
      mx = fmaxf(mx, __shfl_xor(mx, 1));
      mx = fmaxf(mx, __shfl_xor(mx, 2));
      mx = fmaxf(mx, __shfl_xor(mx, 4));
      mx = fmaxf(mx, __shfl_xor(mx, 8));
      float mn = fmaxf(mrow[r], mx);
      float al = __expf(mrow[r] - mn);
      mrow[r] = mn;
      float ps = 0.f;
      #pragma unroll
      for (int kb = 0; kb < 4; ++kb) {
        float p = __expf(sc[kb][r] * scale - mn);
        sc[kb][r] = p;
        ps += p;
      }
      ps += __shfl_xor(ps, 1); ps += __shfl_xor(ps, 2);
      ps += __shfl_xor(ps, 4); ps += __shfl_xor(ps, 8);
      lrow[r] = lrow[r] * al + ps;
      alpha[r] = al;
    }

    // P -> wave-private LDS (bf16) for PV A-operand
    #pragma unroll
    for (int kb = 0; kb < 4; ++kb)
      #pragma unroll
      for (int r = 0; r < 4; ++r)
        Pw[(g*4 + r) * 72 + kb*16 + lr] = (__bf16)sc[kb][r];

    // rescale accumulator
    #pragma unroll
    for (int db = 0; db < 8; ++db)
      #pragma unroll
      for (int r = 0; r < 4; ++r) acc[db][r] *= alpha[r];

    // PV
    bf16x8 ap0 = *(const bf16x8*)(Pw + lr * 72 + g * 8);
    bf16x8 ap1 = *(const bf16x8*)(Pw + lr * 72 + 32 + g * 8);
    #pragma unroll
    for (int db = 0; db < 8; ++db) {
      bf16x8 v0 = *(const bf16x8*)(Vl + (db*16 + lr) * 72 + g * 8);
      bf16x8 v1 = *(const bf16x8*)(Vl + (db*16 + lr) * 72 + (4 + g) * 8);
      acc[db] = mfma16(ap0, v0, acc[db]);
      acc[db] = mfma16(ap1, v1, acc[db]);
    }
  }

  float rinv[4];
  #pragma unroll
  for (int r = 0; r < 4; ++r) rinv[r] = 1.f / lrow[r];
  #pragma unroll
  for (int db = 0; db < 8; ++db)
    #pragma unroll
    for (int r = 0; r < 4; ++r) {
      int s = q0 + wave*16 + g*4 + r;
      Og[(size_t)s * DMODEL + h * HDIM + db*16 + lr] = (__bf16)(acc[db][r] * rinv[r]);
    }
}

// ---------------- host ----------------
extern "C" void kernel_launch(void* const* d_in, const int* in_sizes, int n_in,
                              void* d_out, int out_size, void* d_ws, size_t ws_size,
                              hipStream_t stream) {
  const float* x_img   = (const float*)d_in[0];
  const float* x_txt   = (const float*)d_in[1];
  const float* img_cos = (const float*)d_in[2];
  const float* img_sin = (const float*)d_in[3];
  const float* txt_cos = (const float*)d_in[4];
  const float* txt_sin = (const float*)d_in[5];
  const float* Wq  = (const float*)d_in[6];  const float* bq  = (const float*)d_in[7];
  const float* Wk  = (const float*)d_in[8];  const float* bk  = (const float*)d_in[9];
  const float* Wv  = (const float*)d_in[10]; const float* bv  = (const float*)d_in[11];
  const float* Waq = (const float*)d_in[12]; const float* baq = (const float*)d_in[13];
  const float* Wak = (const float*)d_in[14]; const float* bak = (const float*)d_in[15];
  const float* Wav = (const float*)d_in[16]; const float* bav = (const float*)d_in[17];
  const float* Wo  = (const float*)d_in[18]; const float* bo  = (const float*)d_in[19];
  const float* Wao = (const float*)d_in[20]; const float* bao = (const float*)d_in[21];

  __bf16* ws = (__bf16*)d_ws;            // ~104 MB of bf16 scratch
  __bf16* Qb  = ws;
  __bf16* Kb  = Qb + SZ_QKV;
  __bf16* Vb  = Kb + SZ_QKV;
  __bf16* Vtb = Vb + SZ_QKV;
  __bf16* AO  = Vtb + SZ_QKV;
  __bf16* XI  = AO + SZ_AO;
  __bf16* XT  = XI + SZ_XIMG;
  __bf16* WS1 = XT + SZ_XTXT;            // reused weight slot

  float* out_img = (float*)d_out;
  float* out_txt = out_img + (size_t)S_IMG * DMODEL;

  #define CVT(src, dst, n) cvt_f32_bf16<<<dim3((unsigned)((n)/2048)), dim3(256), 0, stream>>>((src), (dst), (int)(n))

  CVT(x_img, XI, SZ_XIMG);
  CVT(x_txt, XT, SZ_XTXT);

  CVT(Wq, WS1, SZ_W);
  gemm_bt<0><<<dim3(16, 24), 256, 0, stream>>>(XI, WS1, bq, Qb, 2048, DMODEL, S_TXT);
  CVT(Waq, WS1, SZ_W);
  gemm_bt<0><<<dim3(2, 24), 256, 0, stream>>>(XT, WS1, baq, Qb, 256, DMODEL, 0);
  CVT(Wk, WS1, SZ_W);
  gemm_bt<0><<<dim3(16, 24), 256, 0, stream>>>(XI, WS1, bk, Kb, 2048, DMODEL, S_TXT);
  CVT(Wak, WS1, SZ_W);
  gemm_bt<0><<<dim3(2, 24), 256, 0, stream>>>(XT, WS1, bak, Kb, 256, DMODEL, 0);
  CVT(Wv, WS1, SZ_W);
  gemm_bt<0><<<dim3(16, 24), 256, 0, stream>>>(XI, WS1, bv, Vb, 2048, DMODEL, S_TXT);
  CVT(Wav, WS1, SZ_W);
  gemm_bt<0><<<dim3(2, 24), 256, 0, stream>>>(XT, WS1, bav, Vb, 256, DMODEL, 0);

  rope_kernel<<<dim3(3456, 2), 256, 0, stream>>>(Qb, Kb, img_cos, img_sin, txt_cos, txt_sin);
  transpose_v<<<dim3(36, 24), 128, 0, stream>>>(Vb, Vtb);
  flash_attn<<<dim3(36, 24), 256, 0, stream>>>(Qb, Kb, Vtb, AO);

  CVT(Wo, WS1, SZ_W);
  gemm_bt<1><<<dim3(16, 24), 256, 0, stream>>>(AO + (size_t)S_TXT * DMODEL, WS1, bo, out_img, 2048, DMODEL, 0);
  CVT(Wao, WS1, SZ_W);
  gemm_bt<1><<<dim3(2, 24), 256, 0, stream>>>(AO, WS1, bao, out_txt, 256, DMODEL, 0);

  #undef CVT
  (void)in_sizes; (void)n_in; (void)out_size; (void)ws_size;
}

// Round 3
// 701.642 us; speedup vs baseline: 1.0697x; 1.0697x over previous
//
#include <hip/hip_runtime.h>
#include <cstdint>
#include <cstddef>

typedef __bf16 bf16x8 __attribute__((ext_vector_type(8)));
typedef float  f32x4  __attribute__((ext_vector_type(4)));

#define S_TXT 256
#define S_IMG 2048
#define S_TOT 2304
#define NHEAD 24
#define HDIM  128
#define DMODEL 3072

static constexpr size_t SZ_QKV  = (size_t)NHEAD * S_TOT * HDIM;
static constexpr size_t SZ_AO   = (size_t)S_TOT * DMODEL;
static constexpr size_t SZ_XIMG = (size_t)S_IMG * DMODEL;
static constexpr size_t SZ_XTXT = (size_t)S_TXT * DMODEL;

__device__ __forceinline__ f32x4 mfma16(bf16x8 a, bf16x8 b, f32x4 c) {
  return __builtin_amdgcn_mfma_f32_16x16x32_bf16(a, b, c, 0, 0, 0);
}

// ---------------- fp32 -> bf16 convert (RNE) ----------------
__global__ __launch_bounds__(256) void cvt_f32_bf16(const float* __restrict__ in,
                                                    __bf16* __restrict__ out, int n) {
  int i = (blockIdx.x * 256 + threadIdx.x) * 8;
  if (i + 8 > n) return;
  f32x4 a = *(const f32x4*)(in + i);
  f32x4 b = *(const f32x4*)(in + i + 4);
  bf16x8 r;
  r[0]=(__bf16)a[0]; r[1]=(__bf16)a[1]; r[2]=(__bf16)a[2]; r[3]=(__bf16)a[3];
  r[4]=(__bf16)b[0]; r[5]=(__bf16)b[1]; r[6]=(__bf16)b[2]; r[7]=(__bf16)b[3];
  *(bf16x8*)(out + i) = r;
}

// ---------------- RoPE in-place; Q additionally pre-scaled by 1/sqrt(HD) ----------------
__global__ __launch_bounds__(256) void rope_kernel(__bf16* __restrict__ Qb, __bf16* __restrict__ Kb,
    const float* __restrict__ icos, const float* __restrict__ isin,
    const float* __restrict__ tcos, const float* __restrict__ tsin) {
  size_t idx = ((size_t)blockIdx.x * 256 + threadIdx.x) * 8;
  __bf16* X; float mult;
  if (blockIdx.y) { X = Kb; mult = 1.0f; }
  else            { X = Qb; mult = 0.08838834764831845f; }
  int d = (int)(idx & 127);
  int s = (int)((idx >> 7) % S_TOT);
  const float *cp, *sp; int ss;
  if (s < S_TXT) { cp = tcos; sp = tsin; ss = s; }
  else           { cp = icos; sp = isin; ss = s - S_TXT; }
  const float* cb = cp + (size_t)ss * HDIM + d;
  const float* sb = sp + (size_t)ss * HDIM + d;
  f32x4 c0 = *(const f32x4*)(cb);
  f32x4 c1 = *(const f32x4*)(cb + 4);
  f32x4 s0 = *(const f32x4*)(sb);
  f32x4 s1 = *(const f32x4*)(sb + 4);
  bf16x8 x = *(const bf16x8*)(X + idx);
  float xf[8];
  #pragma unroll
  for (int j = 0; j < 8; ++j) xf[j] = (float)x[j];
  bf16x8 o;
  o[0] = (__bf16)((xf[0]*c0[0] - xf[1]*s0[0]) * mult);
  o[1] = (__bf16)((xf[1]*c0[1] + xf[0]*s0[1]) * mult);
  o[2] = (__bf16)((xf[2]*c0[2] - xf[3]*s0[2]) * mult);
  o[3] = (__bf16)((xf[3]*c0[3] + xf[2]*s0[3]) * mult);
  o[4] = (__bf16)((xf[4]*c1[0] - xf[5]*s1[0]) * mult);
  o[5] = (__bf16)((xf[5]*c1[1] + xf[4]*s1[1]) * mult);
  o[6] = (__bf16)((xf[6]*c1[2] - xf[7]*s1[2]) * mult);
  o[7] = (__bf16)((xf[7]*c1[3] + xf[6]*s1[3]) * mult);
  *(bf16x8*)(X + idx) = o;
}

// ---------------- V [h][s][d] -> Vt [h][d][s] ----------------
__global__ __launch_bounds__(128) void transpose_v(const __bf16* __restrict__ V,
                                                   __bf16* __restrict__ Vt) {
  int h = blockIdx.y, s0 = blockIdx.x * 64, d = threadIdx.x;
  const __bf16* src = V + ((size_t)h * S_TOT + s0) * HDIM + d;
  __bf16 tmp[64];
  #pragma unroll
  for (int k = 0; k < 64; ++k) tmp[k] = src[(size_t)k * HDIM];
  __bf16* dst = Vt + ((size_t)h * HDIM + d) * S_TOT + s0;
  #pragma unroll
  for (int k = 0; k < 8; ++k) {
    bf16x8 v;
    #pragma unroll
    for (int j = 0; j < 8; ++j) v[j] = tmp[k*8 + j];
    *(bf16x8*)(dst + k*8) = v;
  }
}

// ---------------- fused GEMM ----------------
// C[M,3072] = A[M,3072](bf16) * W[3072,3072]^T(fp32, cvt in-flight) + bias
// MODE 0: grid (18, 72): x<16 img tile, x>=16 txt tile; y/24 selects Q/K/V;
//         bf16 out scattered to [head][s][hd].
// MODE 1: grid (18, 24): fp32 row-major out (img->O0[0], txt->O1[0]).
struct GArgs {
  const __bf16* A0; const __bf16* A1;
  const float* W0[3]; const float* W1[3];
  const float* b0[3]; const float* b1[3];
  void* O0[3]; void* O1[3];
};

template<int MODE>
__global__ __launch_bounds__(256, 3) void gemm_all(GArgs ga) {
  const int tid = threadIdx.x;
  const int lane = tid & 63, wave = tid >> 6;
  const int wr = wave >> 1, wc = wave & 1;
  const int g = lane >> 4, lr = lane & 15;
  const int x7 = lr & 7;
  const int wsel = (MODE == 0) ? ((int)blockIdx.y / 24) : 0;
  const int ny   = (MODE == 0) ? ((int)blockIdx.y % 24) : (int)blockIdx.y;
  const bool txt = blockIdx.x >= 16;
  const __bf16* A   = txt ? ga.A1 : ga.A0;
  const float* Wf   = txt ? ga.W1[wsel] : ga.W0[wsel];
  const float* bias = txt ? ga.b1[wsel] : ga.b0[wsel];
  const int m0 = (txt ? (int)blockIdx.x - 16 : (int)blockIdx.x) * 128;
  const int n0 = ny * 128;

  __shared__ __align__(16) __bf16 As[128 * 64];
  __shared__ __align__(16) __bf16 Bs[128 * 64];

  // A staging via global_load_lds: wave w covers LDS bytes [w*4096 + i*1024, +1024)
  // lane L -> row w*32 + i*8 + (L>>3), phys slot L&7 -> logical chunk (L&7)^(L>>3)
  const int srow = wave * 32 + (lane >> 3);
  const int scol = ((lane & 7) ^ (lane >> 3)) * 8;
  const __bf16* Ap = A + (size_t)(m0 + srow) * DMODEL + scol;
  char* Asl = (char*)As + wave * 4096;

  // B staging (fp32 weights): lane owns row wave*32 + i*8 + (L>>3), chunk L&7,
  // swizzled phys slot (L&7)^(L>>3)
  const int brow = wave * 32 + (lane >> 3);
  const int bws  = brow * 128 + (((lane & 7) ^ ((lane >> 3) & 7)) << 4);
  const float* Bp = Wf + (size_t)(n0 + brow) * DMODEL + (lane & 7) * 8;

  f32x4 acc[4][4];
  #pragma unroll
  for (int i = 0; i < 4; ++i)
    #pragma unroll
    for (int j = 0; j < 4; ++j) acc[i][j] = (f32x4){0.f,0.f,0.f,0.f};

  f32x4 pre[4][2];
  #pragma unroll
  for (int i = 0; i < 4; ++i) {
    pre[i][0] = *(const f32x4*)(Bp + (size_t)i * 8 * DMODEL);
    pre[i][1] = *(const f32x4*)(Bp + (size_t)i * 8 * DMODEL + 4);
  }

  const int nk = DMODEL / 64;
  for (int kt = 0; kt < nk; ++kt) {
    const __bf16* Apk = Ap + kt * 64;
    #pragma unroll
    for (int i = 0; i < 4; ++i) {
      __builtin_amdgcn_global_load_lds(
          (const __attribute__((address_space(1))) void*)(Apk + (size_t)i * 8 * DMODEL),
          (__attribute__((address_space(3))) void*)(Asl + i * 1024), 16, 0, 0);
    }
    // B: cvt prefetched fp32 -> bf16, swizzled ds_write
    // BUGFIX r2->r3: dest row stride is i*1024 (8 rows x 128B), NOT i*4096
    #pragma unroll
    for (int i = 0; i < 4; ++i) {
      bf16x8 bw;
      #pragma unroll
      for (int j = 0; j < 4; ++j) {
        bw[j]     = (__bf16)pre[i][0][j];
        bw[4 + j] = (__bf16)pre[i][1][j];
      }
      *(bf16x8*)((char*)Bs + bws + i * 1024) = bw;
    }
    if (kt + 1 < nk) {
      const float* Bpk = Bp + (kt + 1) * 64;
      #pragma unroll
      for (int i = 0; i < 4; ++i) {
        pre[i][0] = *(const f32x4*)(Bpk + (size_t)i * 8 * DMODEL);
        pre[i][1] = *(const f32x4*)(Bpk + (size_t)i * 8 * DMODEL + 4);
      }
    }
    __syncthreads();   // drains vmcnt(0)+lgkmcnt(0): A tile + B writes resident

    #pragma unroll
    for (int ks = 0; ks < 2; ++ks) {
      bf16x8 af[4], bfr[4];
      #pragma unroll
      for (int i = 0; i < 4; ++i) {
        af[i]  = *(const bf16x8*)((char*)As + (wr*64 + i*16 + lr) * 128 + (((ks*4 + g) ^ x7) << 4));
        bfr[i] = *(const bf16x8*)((char*)Bs + (wc*64 + i*16 + lr) * 128 + (((ks*4 + g) ^ x7) << 4));
      }
      #pragma unroll
      for (int i = 0; i < 4; ++i)
        #pragma unroll
        for (int j = 0; j < 4; ++j)
          acc[i][j] = mfma16(af[i], bfr[j], acc[i][j]);
    }
    __syncthreads();   // all frag reads done before next overwrite
  }

  float bv[4];
  #pragma unroll
  for (int j = 0; j < 4; ++j) bv[j] = bias[n0 + wc*64 + j*16 + lr];

  if (MODE == 0) {
    __bf16* Qp = (__bf16*)(txt ? ga.O1[wsel] : ga.O0[wsel]);
    const int s_off = txt ? 0 : S_TXT;
    #pragma unroll
    for (int i = 0; i < 4; ++i)
      #pragma unroll
      for (int j = 0; j < 4; ++j)
        #pragma unroll
        for (int r = 0; r < 4; ++r) {
          int s  = s_off + m0 + wr*64 + i*16 + g*4 + r;
          int hd = wc*64 + j*16 + lr;
          Qp[((size_t)ny * S_TOT + s) * HDIM + hd] = (__bf16)(acc[i][j][r] + bv[j]);
        }
  } else {
    float* Cf = (float*)(txt ? ga.O1[0] : ga.O0[0]);
    #pragma unroll
    for (int i = 0; i < 4; ++i)
      #pragma unroll
      for (int j = 0; j < 4; ++j)
        #pragma unroll
        for (int r = 0; r < 4; ++r) {
          int m = m0 + wr*64 + i*16 + g*4 + r;
          int n = n0 + wc*64 + j*16 + lr;
          Cf[(size_t)m * DMODEL + n] = acc[i][j][r] + bv[j];
        }
  }
}

// ---------------- flash attention ----------------
// grid (36, 24), 256 thr = 4 waves x 16 q-rows, KV tile 64. Q pre-scaled.
// All LDS tiles linear with byte ^= (row&7)<<4 swizzle (no pads).
__global__ __launch_bounds__(256, 4) void flash_attn(
    const __bf16* __restrict__ Qg, const __bf16* __restrict__ Kg,
    const __bf16* __restrict__ Vt, __bf16* __restrict__ Og)
{
  const int h = blockIdx.y;
  const int q0 = blockIdx.x * 64;
  const int tid = threadIdx.x;
  const int lane = tid & 63, wave = tid >> 6;
  const int g = lane >> 4, lr = lane & 15;
  const int x7 = lr & 7;

  __shared__ __align__(16) __bf16 Kl[64 * 128];    // [kv][d]   256B rows
  __shared__ __align__(16) __bf16 Vl[128 * 64];    // [d][kv]   128B rows
  __shared__ __align__(16) __bf16 Pl[4][16 * 64];  // per-wave [q][kv] 128B rows
  char* Kc = (char*)Kl;
  char* Vc = (char*)Vl;
  char* Pc = (char*)&Pl[wave][0];

  bf16x8 qf[4];
  {
    const __bf16* qp = Qg + ((size_t)h * S_TOT + q0 + wave*16 + lr) * HDIM + g * 8;
    #pragma unroll
    for (int kb = 0; kb < 4; ++kb) qf[kb] = *(const bf16x8*)(qp + kb * 32);
  }

  f32x4 acc[8];
  #pragma unroll
  for (int i = 0; i < 8; ++i) acc[i] = (f32x4){0.f,0.f,0.f,0.f};
  float mrow[4] = {-__builtin_inff(), -__builtin_inff(), -__builtin_inff(), -__builtin_inff()};
  float lrow[4] = {0.f, 0.f, 0.f, 0.f};

  const int krow = tid >> 4, kc = tid & 15;
  const int vrow = tid >> 3, vc = tid & 7;
  const __bf16* Kbase = Kg + (size_t)h * S_TOT * HDIM;
  const __bf16* Vbase = Vt + (size_t)h * HDIM * S_TOT;

  const int kwoff = krow * 256 + ((kc ^ (krow & 7)) << 4);
  const int vwoff = vrow * 128 + ((vc ^ (vrow & 7)) << 4);

  bf16x8 kreg[4], vreg[4];
  #pragma unroll
  for (int i = 0; i < 4; ++i) {
    kreg[i] = *(const bf16x8*)(Kbase + (size_t)(i*16 + krow) * HDIM + kc * 8);
    vreg[i] = *(const bf16x8*)(Vbase + (size_t)(i*32 + vrow) * S_TOT + vc * 8);
  }

  for (int t = 0; t < S_TOT / 64; ++t) {
    asm volatile("" ::: "memory");
    __builtin_amdgcn_s_barrier();           // all waves done reading prev tile
    asm volatile("" ::: "memory");
    #pragma unroll
    for (int i = 0; i < 4; ++i) {
      *(bf16x8*)(Kc + kwoff + i * 4096) = kreg[i];
      *(bf16x8*)(Vc + vwoff + i * 4096) = vreg[i];
    }
    if (t + 1 < S_TOT / 64) {
      int kv1 = (t + 1) * 64;
      #pragma unroll
      for (int i = 0; i < 4; ++i) {
        kreg[i] = *(const bf16x8*)(Kbase + (size_t)(kv1 + i*16 + krow) * HDIM + kc * 8);
        vreg[i] = *(const bf16x8*)(Vbase + (size_t)(i*32 + vrow) * S_TOT + kv1 + vc * 8);
      }
    }
    asm volatile("s_waitcnt lgkmcnt(0)" ::: "memory");  // LDS writes visible; prefetch stays in flight
    __builtin_amdgcn_s_barrier();
    asm volatile("" ::: "memory");

    // QK^T (Q pre-scaled): sc[kb] rows q=g*4+r, col kv=kb*16+lr
    f32x4 sc[4];
    __builtin_amdgcn_s_setprio(1);
    #pragma unroll
    for (int kb = 0; kb < 4; ++kb) {
      f32x4 s4 = (f32x4){0.f,0.f,0.f,0.f};
      #pragma unroll
      for (int dk = 0; dk < 4; ++dk) {
        bf16x8 kf = *(const bf16x8*)(Kc + (kb*16 + lr) * 256 + (((dk*4 + g) ^ x7) << 4));
        s4 = mfma16(qf[dk], kf, s4);
      }
      sc[kb] = s4;
    }
    __builtin_amdgcn_s_setprio(0);

    // online softmax (fp32)
    float alpha[4];
    #pragma unroll
    for (int r = 0; r < 4; ++r) {
      float mx = fmaxf(fmaxf(sc[0][r], sc[1][r]), fmaxf(sc[2][r], sc[3][r]));
      mx = fmaxf(mx, __shfl_xor(mx, 1));
      mx = fmaxf(mx, __shfl_xor(mx, 2));
      mx = fmaxf(mx, __shfl_xor(mx, 4));
      mx = fmaxf(mx, __shfl_xor(mx, 8));
      float mn = fmaxf(mrow[r], mx);
      float al = __expf(mrow[r] - mn);
      mrow[r] = mn;
      float ps = 0.f;
      #pragma unroll
      for (int kb = 0; kb < 4; ++kb) {
        float p = __expf(sc[kb][r] - mn);
        sc[kb][r] = p;
        ps += p;
      }
      ps += __shfl_xor(ps, 1); ps += __shfl_xor(ps, 2);
      ps += __shfl_xor(ps, 4); ps += __shfl_xor(ps, 8);
      lrow[r] = lrow[r] * al + ps;
      alpha[r] = al;
    }

    // P -> wave-private LDS (bf16), swizzled
    #pragma unroll
    for (int kb = 0; kb < 4; ++kb)
      #pragma unroll
      for (int r = 0; r < 4; ++r) {
        int row = g*4 + r;
        *(__bf16*)(Pc + (((row * 128) + (kb*16 + lr) * 2) ^ ((row & 7) << 4))) = (__bf16)sc[kb][r];
      }

    // rescale accumulator
    #pragma unroll
    for (int db = 0; db < 8; ++db)
      #pragma unroll
      for (int r = 0; r < 4; ++r) acc[db][r] *= alpha[r];

    // PV
    bf16x8 ap0 = *(const bf16x8*)(Pc + ((lr * 128 + g * 16) ^ (x7 << 4)));
    bf16x8 ap1 = *(const bf16x8*)(Pc + ((lr * 128 + (4 + g) * 16) ^ (x7 << 4)));
    __builtin_amdgcn_s_setprio(1);
    #pragma unroll
    for (int db = 0; db < 8; ++db) {
      bf16x8 v0 = *(const bf16x8*)(Vc + (db*16 + lr) * 128 + ((g ^ x7) << 4));
      bf16x8 v1 = *(const bf16x8*)(Vc + (db*16 + lr) * 128 + (((4 + g) ^ x7) << 4));
      acc[db] = mfma16(ap0, v0, acc[db]);
      acc[db] = mfma16(ap1, v1, acc[db]);
    }
    __builtin_amdgcn_s_setprio(0);
  }

  float rinv[4];
  #pragma unroll
  for (int r = 0; r < 4; ++r) rinv[r] = 1.f / lrow[r];
  #pragma unroll
  for (int db = 0; db < 8; ++db)
    #pragma unroll
    for (int r = 0; r < 4; ++r) {
      int s = q0 + wave*16 + g*4 + r;
      Og[(size_t)s * DMODEL + h * HDIM + db*16 + lr] = (__bf16)(acc[db][r] * rinv[r]);
    }
}

// ---------------- host ----------------
extern "C" void kernel_launch(void* const* d_in, const int* in_sizes, int n_in,
                              void* d_out, int out_size, void* d_ws, size_t ws_size,
                              hipStream_t stream) {
  const float* x_img   = (const float*)d_in[0];
  const float* x_txt   = (const float*)d_in[1];
  const float* img_cos = (const float*)d_in[2];
  const float* img_sin = (const float*)d_in[3];
  const float* txt_cos = (const float*)d_in[4];
  const float* txt_sin = (const float*)d_in[5];
  const float* Wq  = (const float*)d_in[6];  const float* bq  = (const float*)d_in[7];
  const float* Wk  = (const float*)d_in[8];  const float* bk  = (const float*)d_in[9];
  const float* Wv  = (const float*)d_in[10]; const float* bv  = (const float*)d_in[11];
  const float* Waq = (const float*)d_in[12]; const float* baq = (const float*)d_in[13];
  const float* Wak = (const float*)d_in[14]; const float* bak = (const float*)d_in[15];
  const float* Wav = (const float*)d_in[16]; const float* bav = (const float*)d_in[17];
  const float* Wo  = (const float*)d_in[18]; const float* bo  = (const float*)d_in[19];
  const float* Wao = (const float*)d_in[20]; const float* bao = (const float*)d_in[21];

  __bf16* ws = (__bf16*)d_ws;
  __bf16* Qb  = ws;
  __bf16* Kb  = Qb + SZ_QKV;
  __bf16* Vb  = Kb + SZ_QKV;
  __bf16* Vtb = Vb + SZ_QKV;
  __bf16* AO  = Vtb + SZ_QKV;
  __bf16* XI  = AO + SZ_AO;
  __bf16* XT  = XI + SZ_XIMG;

  float* out_img = (float*)d_out;
  float* out_txt = out_img + (size_t)S_IMG * DMODEL;

  cvt_f32_bf16<<<dim3((unsigned)(SZ_XIMG/2048)), 256, 0, stream>>>(x_img, XI, (int)SZ_XIMG);
  cvt_f32_bf16<<<dim3((unsigned)(SZ_XTXT/2048)), 256, 0, stream>>>(x_txt, XT, (int)SZ_XTXT);

  GArgs gq{};
  gq.A0 = XI; gq.A1 = XT;
  gq.W0[0] = Wq;  gq.W0[1] = Wk;  gq.W0[2] = Wv;
  gq.W1[0] = Waq; gq.W1[1] = Wak; gq.W1[2] = Wav;
  gq.b0[0] = bq;  gq.b0[1] = bk;  gq.b0[2] = bv;
  gq.b1[0] = baq; gq.b1[1] = bak; gq.b1[2] = bav;
  gq.O0[0] = Qb;  gq.O0[1] = Kb;  gq.O0[2] = Vb;
  gq.O1[0] = Qb;  gq.O1[1] = Kb;  gq.O1[2] = Vb;
  gemm_all<0><<<dim3(18, 72), 256, 0, stream>>>(gq);

  rope_kernel<<<dim3(3456, 2), 256, 0, stream>>>(Qb, Kb, img_cos, img_sin, txt_cos, txt_sin);
  transpose_v<<<dim3(36, 24), 128, 0, stream>>>(Vb, Vtb);
  flash_attn<<<dim3(36, 24), 256, 0, stream>>>(Qb, Kb, Vtb, AO);

  GArgs go{};
  go.A0 = AO + (size_t)S_TXT * DMODEL; go.A1 = AO;
  go.W0[0] = Wo;  go.W1[0] = Wao;
  go.b0[0] = bo;  go.b1[0] = bao;
  go.O0[0] = out_img; go.O1[0] = out_txt;
  gemm_all<1><<<dim3(18, 24), 256, 0, stream>>>(go);

  (void)in_sizes; (void)n_in; (void)out_size; (void)ws_size;
}

// Round 4
// 523.780 us; speedup vs baseline: 1.4329x; 1.3396x over previous
//
#include <hip/hip_runtime.h>
#include <cstdint>
#include <cstddef>

typedef __bf16 bf16x8 __attribute__((ext_vector_type(8)));
typedef float  f32x4  __attribute__((ext_vector_type(4)));

#define S_TXT 256
#define S_IMG 2048
#define S_TOT 2304
#define NHEAD 24
#define HDIM  128
#define DMODEL 3072

static constexpr size_t SZ_QKV  = (size_t)NHEAD * S_TOT * HDIM;
static constexpr size_t SZ_AO   = (size_t)S_TOT * DMODEL;
static constexpr size_t SZ_XIMG = (size_t)S_IMG * DMODEL;
static constexpr size_t SZ_XTXT = (size_t)S_TXT * DMODEL;

__device__ __forceinline__ f32x4 mfma16(bf16x8 a, bf16x8 b, f32x4 c) {
  return __builtin_amdgcn_mfma_f32_16x16x32_bf16(a, b, c, 0, 0, 0);
}

// ---------------- fp32 -> bf16 convert (RNE) ----------------
__global__ __launch_bounds__(256) void cvt_f32_bf16(const float* __restrict__ in,
                                                    __bf16* __restrict__ out, int n) {
  int i = (blockIdx.x * 256 + threadIdx.x) * 8;
  if (i + 8 > n) return;
  f32x4 a = *(const f32x4*)(in + i);
  f32x4 b = *(const f32x4*)(in + i + 4);
  bf16x8 r;
  r[0]=(__bf16)a[0]; r[1]=(__bf16)a[1]; r[2]=(__bf16)a[2]; r[3]=(__bf16)a[3];
  r[4]=(__bf16)b[0]; r[5]=(__bf16)b[1]; r[6]=(__bf16)b[2]; r[7]=(__bf16)b[3];
  *(bf16x8*)(out + i) = r;
}

// ---------------- RoPE in-place; Q additionally pre-scaled by 1/sqrt(HD) ----------------
__global__ __launch_bounds__(256) void rope_kernel(__bf16* __restrict__ Qb, __bf16* __restrict__ Kb,
    const float* __restrict__ icos, const float* __restrict__ isin,
    const float* __restrict__ tcos, const float* __restrict__ tsin) {
  size_t idx = ((size_t)blockIdx.x * 256 + threadIdx.x) * 8;
  __bf16* X; float mult;
  if (blockIdx.y) { X = Kb; mult = 1.0f; }
  else            { X = Qb; mult = 0.08838834764831845f; }
  int d = (int)(idx & 127);
  int s = (int)((idx >> 7) % S_TOT);
  const float *cp, *sp; int ss;
  if (s < S_TXT) { cp = tcos; sp = tsin; ss = s; }
  else           { cp = icos; sp = isin; ss = s - S_TXT; }
  const float* cb = cp + (size_t)ss * HDIM + d;
  const float* sb = sp + (size_t)ss * HDIM + d;
  f32x4 c0 = *(const f32x4*)(cb);
  f32x4 c1 = *(const f32x4*)(cb + 4);
  f32x4 s0 = *(const f32x4*)(sb);
  f32x4 s1 = *(const f32x4*)(sb + 4);
  bf16x8 x = *(const bf16x8*)(X + idx);
  float xf[8];
  #pragma unroll
  for (int j = 0; j < 8; ++j) xf[j] = (float)x[j];
  bf16x8 o;
  o[0] = (__bf16)((xf[0]*c0[0] - xf[1]*s0[0]) * mult);
  o[1] = (__bf16)((xf[1]*c0[1] + xf[0]*s0[1]) * mult);
  o[2] = (__bf16)((xf[2]*c0[2] - xf[3]*s0[2]) * mult);
  o[3] = (__bf16)((xf[3]*c0[3] + xf[2]*s0[3]) * mult);
  o[4] = (__bf16)((xf[4]*c1[0] - xf[5]*s1[0]) * mult);
  o[5] = (__bf16)((xf[5]*c1[1] + xf[4]*s1[1]) * mult);
  o[6] = (__bf16)((xf[6]*c1[2] - xf[7]*s1[2]) * mult);
  o[7] = (__bf16)((xf[7]*c1[3] + xf[6]*s1[3]) * mult);
  *(bf16x8*)(X + idx) = o;
}

// ---------------- V [h][s][d] -> Vt [h][d][s] ----------------
__global__ __launch_bounds__(128) void transpose_v(const __bf16* __restrict__ V,
                                                   __bf16* __restrict__ Vt) {
  int h = blockIdx.y, s0 = blockIdx.x * 64, d = threadIdx.x;
  const __bf16* src = V + ((size_t)h * S_TOT + s0) * HDIM + d;
  __bf16 tmp[64];
  #pragma unroll
  for (int k = 0; k < 64; ++k) tmp[k] = src[(size_t)k * HDIM];
  __bf16* dst = Vt + ((size_t)h * HDIM + d) * S_TOT + s0;
  #pragma unroll
  for (int k = 0; k < 8; ++k) {
    bf16x8 v;
    #pragma unroll
    for (int j = 0; j < 8; ++j) v[j] = tmp[k*8 + j];
    *(bf16x8*)(dst + k*8) = v;
  }
}

// ---------------- fused GEMM, BM=256 x BN=128, BK=64 ----------------
// C[M,3072] = A[M,3072](bf16) * W[3072,3072]^T(fp32, cvt in-flight) + bias
// A is a single contiguous [2304][3072] matrix (img rows 0..2047, txt 2048..2303
// for MODE 0; AO s-order for MODE 1). 1D grid, XCD-chunked remap:
//   MODE 0: 648 blocks = 8 XCD x (9 n-rows x 9 m-tiles), m-fastest
//   MODE 1: 216 blocks = 8 XCD x (3 n-rows x 9 m-tiles), m-fastest
// -> each W 128-row panel is fetched into exactly one XCD L2, reused 9x.
struct GArgs {
  const __bf16* A;
  const float* W0[3]; const float* W1[3];   // img / txt weights
  const float* b0[3]; const float* b1[3];
  void* O0[3]; void* O1[3];
};

template<int MODE>
__global__ __launch_bounds__(256, 2) void gemm_all(GArgs ga) {
  const int tid = threadIdx.x;
  const int lane = tid & 63, wave = tid >> 6;
  const int g = lane >> 4, lr = lane & 15;
  const int x7 = lr & 7;

  const int hw = (int)blockIdx.x;
  const int xcd = hw & 7, idx = hw >> 3;
  const int bx = idx % 9;
  const int nglob = (MODE == 0) ? (xcd * 9 + idx / 9) : (xcd * 3 + idx / 9);
  const int wsel = (MODE == 0) ? nglob / 24 : 0;
  const int ny   = (MODE == 0) ? nglob % 24 : nglob;
  const bool txt = (MODE == 0) ? (bx == 8) : (bx == 0);
  const int m0 = bx * 256;
  const int n0 = ny * 128;
  const float* Wf   = txt ? ga.W1[wsel] : ga.W0[wsel];
  const float* bias = txt ? ga.b1[wsel] : ga.b0[wsel];

  __shared__ __align__(16) __bf16 As[256 * 64];   // 32 KB
  __shared__ __align__(16) __bf16 Bs[128 * 64];   // 16 KB

  // A staging via global_load_lds, 8 issues of 4KB (32 rows each):
  // issue i, wave w, lane l -> LDS byte i*4096 + w*1024 + l*16
  //   = row (i*32 + w*8 + (l>>3)), phys slot l&7; logical chunk = (l&7)^(row&7)
  const int sr8 = lane >> 3;
  const int sch = (lane & 7) ^ sr8;
  const __bf16* Ap = ga.A + (size_t)(m0 + wave * 8 + sr8) * DMODEL + sch * 8;
  char* Asl = (char*)As + wave * 1024;

  // W staging: pass p (0..3): row = p*32 + (tid>>3), f32 chunk-pair = tid&7
  // (32 rows x 256B contiguous per pass -> coalesced)
  const int wrow = tid >> 3;
  const int wch  = tid & 7;
  const float* Bp = Wf + (size_t)(n0 + wrow) * DMODEL + wch * 8;

  f32x4 acc[4][8];
  #pragma unroll
  for (int i = 0; i < 4; ++i)
    #pragma unroll
    for (int j = 0; j < 8; ++j) acc[i][j] = (f32x4){0.f,0.f,0.f,0.f};

  f32x4 pre[4][2];
  #pragma unroll
  for (int p = 0; p < 4; ++p) {
    pre[p][0] = *(const f32x4*)(Bp + (size_t)p * 32 * DMODEL);
    pre[p][1] = *(const f32x4*)(Bp + (size_t)p * 32 * DMODEL + 4);
  }

  const int nk = DMODEL / 64;
  for (int kt = 0; kt < nk; ++kt) {
    const __bf16* Apk = Ap + kt * 64;
    #pragma unroll
    for (int i = 0; i < 8; ++i) {
      __builtin_amdgcn_global_load_lds(
          (const __attribute__((address_space(1))) void*)(Apk + (size_t)i * 32 * DMODEL),
          (__attribute__((address_space(3))) void*)(Asl + i * 4096), 16, 0, 0);
    }
    // W: cvt prefetched fp32 -> bf16, swizzled ds_write_b128
    #pragma unroll
    for (int p = 0; p < 4; ++p) {
      bf16x8 bw;
      #pragma unroll
      for (int j = 0; j < 4; ++j) {
        bw[j]     = (__bf16)pre[p][0][j];
        bw[4 + j] = (__bf16)pre[p][1][j];
      }
      int row = p * 32 + wrow;
      *(bf16x8*)((char*)Bs + row * 128 + ((wch ^ (row & 7)) << 4)) = bw;
    }
    if (kt + 1 < nk) {
      const float* Bpk = Bp + (kt + 1) * 64;
      #pragma unroll
      for (int p = 0; p < 4; ++p) {
        pre[p][0] = *(const f32x4*)(Bpk + (size_t)p * 32 * DMODEL);
        pre[p][1] = *(const f32x4*)(Bpk + (size_t)p * 32 * DMODEL + 4);
      }
    }
    __syncthreads();   // drains vmcnt+lgkmcnt: A tile + B writes resident

    #pragma unroll
    for (int ks = 0; ks < 2; ++ks) {
      bf16x8 af[4], bfr[8];
      #pragma unroll
      for (int i = 0; i < 4; ++i)
        af[i] = *(const bf16x8*)((char*)As + (wave*64 + i*16 + lr) * 128 + (((ks*4 + g) ^ x7) << 4));
      #pragma unroll
      for (int j = 0; j < 8; ++j)
        bfr[j] = *(const bf16x8*)((char*)Bs + (j*16 + lr) * 128 + (((ks*4 + g) ^ x7) << 4));
      #pragma unroll
      for (int i = 0; i < 4; ++i)
        #pragma unroll
        for (int j = 0; j < 8; ++j)
          acc[i][j] = mfma16(af[i], bfr[j], acc[i][j]);
    }
    __syncthreads();   // all frag reads done before next overwrite
  }

  float bv[8];
  #pragma unroll
  for (int j = 0; j < 8; ++j) bv[j] = bias[n0 + j*16 + lr];

  if (MODE == 0) {
    __bf16* Qp = (__bf16*)(txt ? ga.O1[wsel] : ga.O0[wsel]);
    const int sbase = txt ? 0 : m0 + S_TXT;
    #pragma unroll
    for (int i = 0; i < 4; ++i)
      #pragma unroll
      for (int j = 0; j < 8; ++j)
        #pragma unroll
        for (int r = 0; r < 4; ++r) {
          int s  = sbase + wave*64 + i*16 + g*4 + r;
          int hd = j*16 + lr;
          Qp[((size_t)ny * S_TOT + s) * HDIM + hd] = (__bf16)(acc[i][j][r] + bv[j]);
        }
  } else {
    float* Cf = (float*)(txt ? ga.O1[0] : ga.O0[0]);
    const int rbase = txt ? 0 : m0 - S_TXT;
    #pragma unroll
    for (int i = 0; i < 4; ++i)
      #pragma unroll
      for (int j = 0; j < 8; ++j)
        #pragma unroll
        for (int r = 0; r < 4; ++r) {
          int m = rbase + wave*64 + i*16 + g*4 + r;
          int n = n0 + j*16 + lr;
          Cf[(size_t)m * DMODEL + n] = acc[i][j][r] + bv[j];
        }
  }
}

// ---------------- flash attention ----------------
// grid (36, 24), 256 thr = 4 waves x 16 q-rows, KV tile 64. Q pre-scaled.
// All LDS tiles linear with byte ^= (row&7)<<4 swizzle (no pads).
__global__ __launch_bounds__(256, 3) void flash_attn(
    const __bf16* __restrict__ Qg, const __bf16* __restrict__ Kg,
    const __bf16* __restrict__ Vt, __bf16* __restrict__ Og)
{
  const int h = blockIdx.y;
  const int q0 = blockIdx.x * 64;
  const int tid = threadIdx.x;
  const int lane = tid & 63, wave = tid >> 6;
  const int g = lane >> 4, lr = lane & 15;
  const int x7 = lr & 7;

  __shared__ __align__(16) __bf16 Kl[64 * 128];    // [kv][d]   256B rows
  __shared__ __align__(16) __bf16 Vl[128 * 64];    // [d][kv]   128B rows
  __shared__ __align__(16) __bf16 Pl[4][16 * 64];  // per-wave [q][kv] 128B rows
  char* Kc = (char*)Kl;
  char* Vc = (char*)Vl;
  char* Pc = (char*)&Pl[wave][0];

  bf16x8 qf[4];
  {
    const __bf16* qp = Qg + ((size_t)h * S_TOT + q0 + wave*16 + lr) * HDIM + g * 8;
    #pragma unroll
    for (int kb = 0; kb < 4; ++kb) qf[kb] = *(const bf16x8*)(qp + kb * 32);
  }

  f32x4 acc[8];
  #pragma unroll
  for (int i = 0; i < 8; ++i) acc[i] = (f32x4){0.f,0.f,0.f,0.f};
  float mrow[4] = {-__builtin_inff(), -__builtin_inff(), -__builtin_inff(), -__builtin_inff()};
  float lrow[4] = {0.f, 0.f, 0.f, 0.f};

  const int krow = tid >> 4, kc = tid & 15;
  const int vrow = tid >> 3, vc = tid & 7;
  const __bf16* Kbase = Kg + (size_t)h * S_TOT * HDIM;
  const __bf16* Vbase = Vt + (size_t)h * HDIM * S_TOT;

  const int kwoff = krow * 256 + ((kc ^ (krow & 7)) << 4);
  const int vwoff = vrow * 128 + ((vc ^ (vrow & 7)) << 4);

  bf16x8 kreg[4], vreg[4];
  #pragma unroll
  for (int i = 0; i < 4; ++i) {
    kreg[i] = *(const bf16x8*)(Kbase + (size_t)(i*16 + krow) * HDIM + kc * 8);
    vreg[i] = *(const bf16x8*)(Vbase + (size_t)(i*32 + vrow) * S_TOT + vc * 8);
  }

  for (int t = 0; t < S_TOT / 64; ++t) {
    asm volatile("" ::: "memory");
    __builtin_amdgcn_s_barrier();           // all waves done reading prev tile
    asm volatile("" ::: "memory");
    #pragma unroll
    for (int i = 0; i < 4; ++i) {
      *(bf16x8*)(Kc + kwoff + i * 4096) = kreg[i];
      *(bf16x8*)(Vc + vwoff + i * 4096) = vreg[i];
    }
    if (t + 1 < S_TOT / 64) {
      int kv1 = (t + 1) * 64;
      #pragma unroll
      for (int i = 0; i < 4; ++i) {
        kreg[i] = *(const bf16x8*)(Kbase + (size_t)(kv1 + i*16 + krow) * HDIM + kc * 8);
        vreg[i] = *(const bf16x8*)(Vbase + (size_t)(i*32 + vrow) * S_TOT + kv1 + vc * 8);
      }
    }
    asm volatile("s_waitcnt lgkmcnt(0)" ::: "memory");  // LDS writes visible; prefetch stays in flight
    __builtin_amdgcn_s_barrier();
    asm volatile("" ::: "memory");

    // QK^T (Q pre-scaled): sc[kb] rows q=g*4+r, col kv=kb*16+lr
    f32x4 sc[4];
    __builtin_amdgcn_s_setprio(1);
    #pragma unroll
    for (int kb = 0; kb < 4; ++kb) {
      f32x4 s4 = (f32x4){0.f,0.f,0.f,0.f};
      #pragma unroll
      for (int dk = 0; dk < 4; ++dk) {
        bf16x8 kf = *(const bf16x8*)(Kc + (kb*16 + lr) * 256 + (((dk*4 + g) ^ x7) << 4));
        s4 = mfma16(qf[dk], kf, s4);
      }
      sc[kb] = s4;
    }
    __builtin_amdgcn_s_setprio(0);

    // online softmax (fp32)
    float alpha[4];
    #pragma unroll
    for (int r = 0; r < 4; ++r) {
      float mx = fmaxf(fmaxf(sc[0][r], sc[1][r]), fmaxf(sc[2][r], sc[3][r]));
      mx = fmaxf(mx, __shfl_xor(mx, 1));
      mx = fmaxf(mx, __shfl_xor(mx, 2));
      mx = fmaxf(mx, __shfl_xor(mx, 4));
      mx = fmaxf(mx, __shfl_xor(mx, 8));
      float mn = fmaxf(mrow[r], mx);
      float al = __expf(mrow[r] - mn);
      mrow[r] = mn;
      float ps = 0.f;
      #pragma unroll
      for (int kb = 0; kb < 4; ++kb) {
        float p = __expf(sc[kb][r] - mn);
        sc[kb][r] = p;
        ps += p;
      }
      ps += __shfl_xor(ps, 1); ps += __shfl_xor(ps, 2);
      ps += __shfl_xor(ps, 4); ps += __shfl_xor(ps, 8);
      lrow[r] = lrow[r] * al + ps;
      alpha[r] = al;
    }

    // P -> wave-private LDS (bf16), swizzled
    #pragma unroll
    for (int kb = 0; kb < 4; ++kb)
      #pragma unroll
      for (int r = 0; r < 4; ++r) {
        int row = g*4 + r;
        *(__bf16*)(Pc + (((row * 128) + (kb*16 + lr) * 2) ^ ((row & 7) << 4))) = (__bf16)sc[kb][r];
      }

    // rescale accumulator
    #pragma unroll
    for (int db = 0; db < 8; ++db)
      #pragma unroll
      for (int r = 0; r < 4; ++r) acc[db][r] *= alpha[r];

    // PV
    bf16x8 ap0 = *(const bf16x8*)(Pc + ((lr * 128 + g * 16) ^ (x7 << 4)));
    bf16x8 ap1 = *(const bf16x8*)(Pc + ((lr * 128 + (4 + g) * 16) ^ (x7 << 4)));
    __builtin_amdgcn_s_setprio(1);
    #pragma unroll
    for (int db = 0; db < 8; ++db) {
      bf16x8 v0 = *(const bf16x8*)(Vc + (db*16 + lr) * 128 + ((g ^ x7) << 4));
      bf16x8 v1 = *(const bf16x8*)(Vc + (db*16 + lr) * 128 + (((4 + g) ^ x7) << 4));
      acc[db] = mfma16(ap0, v0, acc[db]);
      acc[db] = mfma16(ap1, v1, acc[db]);
    }
    __builtin_amdgcn_s_setprio(0);
  }

  float rinv[4];
  #pragma unroll
  for (int r = 0; r < 4; ++r) rinv[r] = 1.f / lrow[r];
  #pragma unroll
  for (int db = 0; db < 8; ++db)
    #pragma unroll
    for (int r = 0; r < 4; ++r) {
      int s = q0 + wave*16 + g*4 + r;
      Og[(size_t)s * DMODEL + h * HDIM + db*16 + lr] = (__bf16)(acc[db][r] * rinv[r]);
    }
}

// ---------------- host ----------------
extern "C" void kernel_launch(void* const* d_in, const int* in_sizes, int n_in,
                              void* d_out, int out_size, void* d_ws, size_t ws_size,
                              hipStream_t stream) {
  const float* x_img   = (const float*)d_in[0];
  const float* x_txt   = (const float*)d_in[1];
  const float* img_cos = (const float*)d_in[2];
  const float* img_sin = (const float*)d_in[3];
  const float* txt_cos = (const float*)d_in[4];
  const float* txt_sin = (const float*)d_in[5];
  const float* Wq  = (const float*)d_in[6];  const float* bq  = (const float*)d_in[7];
  const float* Wk  = (const float*)d_in[8];  const float* bk  = (const float*)d_in[9];
  const float* Wv  = (const float*)d_in[10]; const float* bv  = (const float*)d_in[11];
  const float* Waq = (const float*)d_in[12]; const float* baq = (const float*)d_in[13];
  const float* Wak = (const float*)d_in[14]; const float* bak = (const float*)d_in[15];
  const float* Wav = (const float*)d_in[16]; const float* bav = (const float*)d_in[17];
  const float* Wo  = (const float*)d_in[18]; const float* bo  = (const float*)d_in[19];
  const float* Wao = (const float*)d_in[20]; const float* bao = (const float*)d_in[21];

  __bf16* ws = (__bf16*)d_ws;
  __bf16* Qb  = ws;
  __bf16* Kb  = Qb + SZ_QKV;
  __bf16* Vb  = Kb + SZ_QKV;
  __bf16* Vtb = Vb + SZ_QKV;
  __bf16* AO  = Vtb + SZ_QKV;
  __bf16* XI  = AO + SZ_AO;          // [2304][3072]: rows 0..2047 img, 2048..2303 txt
  __bf16* XT  = XI + SZ_XIMG;

  float* out_img = (float*)d_out;
  float* out_txt = out_img + (size_t)S_IMG * DMODEL;

  cvt_f32_bf16<<<dim3((unsigned)(SZ_XIMG/2048)), 256, 0, stream>>>(x_img, XI, (int)SZ_XIMG);
  cvt_f32_bf16<<<dim3((unsigned)(SZ_XTXT/2048)), 256, 0, stream>>>(x_txt, XT, (int)SZ_XTXT);

  GArgs gq{};
  gq.A = XI;
  gq.W0[0] = Wq;  gq.W0[1] = Wk;  gq.W0[2] = Wv;
  gq.W1[0] = Waq; gq.W1[1] = Wak; gq.W1[2] = Wav;
  gq.b0[0] = bq;  gq.b0[1] = bk;  gq.b0[2] = bv;
  gq.b1[0] = baq; gq.b1[1] = bak; gq.b1[2] = bav;
  gq.O0[0] = Qb;  gq.O0[1] = Kb;  gq.O0[2] = Vb;
  gq.O1[0] = Qb;  gq.O1[1] = Kb;  gq.O1[2] = Vb;
  gemm_all<0><<<dim3(648), 256, 0, stream>>>(gq);

  rope_kernel<<<dim3(3456, 2), 256, 0, stream>>>(Qb, Kb, img_cos, img_sin, txt_cos, txt_sin);
  transpose_v<<<dim3(36, 24), 128, 0, stream>>>(Vb, Vtb);
  flash_attn<<<dim3(36, 24), 256, 0, stream>>>(Qb, Kb, Vtb, AO);

  GArgs go{};
  go.A = AO;                          // rows 0..255 txt, 256..2303 img
  go.W0[0] = Wo;  go.W1[0] = Wao;
  go.b0[0] = bo;  go.b1[0] = bao;
  go.O0[0] = out_img; go.O1[0] = out_txt;
  gemm_all<1><<<dim3(216), 256, 0, stream>>>(go);

  (void)in_sizes; (void)n_in; (void)out_size; (void)ws_size;
}